// Round 4
// baseline (923.017 us; speedup 1.0000x reference)
//
#include <hip/hip_runtime.h>
#include <hip/hip_bf16.h>
#include <math.h>

#define B_ 2
#define T_ 2048
#define C_ 4096
#define NH_ 32
#define NKV_ 8
#define HD_ 128
#define M_ (B_*T_)              // 4096 rows
#define QKVN_ (NH_*HD_ + 2*NKV_*HD_)  // 6144

using bf16 = __hip_bfloat16;
typedef __bf16 bf16x8 __attribute__((ext_vector_type(8)));
typedef float f32x4 __attribute__((ext_vector_type(4)));

__device__ inline f32x4 mfma16(bf16x8 a, bf16x8 b, f32x4 c) {
    return __builtin_amdgcn_mfma_f32_16x16x32_bf16(a, b, c, 0, 0, 0);
}

// ---------------- cast f32 -> bf16 (vectorized x4) ----------------
__global__ __launch_bounds__(256) void cast_f32_bf16(const float* __restrict__ in,
                                                     bf16* __restrict__ out, int n4) {
    int i = blockIdx.x * 256 + threadIdx.x;
    if (i >= n4) return;
    float4 v = reinterpret_cast<const float4*>(in)[i];
    union { bf16 h[4]; uint2 u; } o;
    o.h[0] = __float2bfloat16(v.x);
    o.h[1] = __float2bfloat16(v.y);
    o.h[2] = __float2bfloat16(v.z);
    o.h[3] = __float2bfloat16(v.w);
    reinterpret_cast<uint2*>(out)[i] = o.u;
}

// ---------------- transpose + cast: in f32 [K][N] -> out bf16 [N][K] ----------------
__global__ __launch_bounds__(256) void transpose_cast(const float* __restrict__ in,
                                                      bf16* __restrict__ out, int K, int N) {
    __shared__ float tile[32][33];
    int tx = threadIdx.x & 31, ty = threadIdx.x >> 5;  // 32 x 8
    int n0 = blockIdx.x << 5, k0 = blockIdx.y << 5;
#pragma unroll
    for (int p = 0; p < 4; ++p)
        tile[p*8 + ty][tx] = in[(size_t)(k0 + p*8 + ty) * N + n0 + tx];
    __syncthreads();
#pragma unroll
    for (int p = 0; p < 4; ++p)
        out[(size_t)(n0 + p*8 + ty) * K + k0 + tx] = __float2bfloat16(tile[tx][p*8 + ty]);
}

// ---------------- 256x256 deep-pipelined GEMM ----------------
__device__ inline void store_out(float* p, float v) { *p = v; }
__device__ inline void store_out(bf16*  p, float v) { *p = __float2bfloat16(v); }

template <typename OutT>
__global__ __launch_bounds__(512, 2) void gemm256(const bf16* __restrict__ A,
                                                  const bf16* __restrict__ Bt,
                                                  OutT* __restrict__ C,
                                                  int M, int N, int K) {
    __shared__ __align__(16) char lds[131072];   // A: [0,64K) B: [64K,128K); each [buf][256][128B]
    const int tid = threadIdx.x;
    const int wid = tid >> 6, lane = tid & 63;
    const int lq = lane & 15, lg = lane >> 4;
    const int wrow = wid >> 2, wcol = wid & 3;

    // XCD chunk swizzle (nwg % 8 == 0)
    const int nwg = gridDim.x;
    const int q8 = nwg >> 3;
    const int wg = (blockIdx.x & 7) * q8 + (blockIdx.x >> 3);
    const int nby = M >> 8;
    const int by = wg % nby, bx = wg / nby;
    const int brow = by << 8, bcol = bx << 8;

    const bf16* Ag = A + (size_t)brow * K;
    const bf16* Bg = Bt + (size_t)bcol * K;
    const int nt = K >> 6;

    const int srow = (wid << 3) + (lane >> 3);              // 0..63 within a 64-row group
    const int schunk = (lane & 7) ^ ((lane >> 3) & 7);      // inverse-swizzle on SOURCE

#define STAGE_MAT(gbase, ldsoff, t2, cbuf)                                              \
    {                                                                                   \
        _Pragma("unroll")                                                               \
        for (int h = 0; h < 2; ++h)                                                     \
            _Pragma("unroll")                                                           \
            for (int l = 0; l < 2; ++l) {                                               \
                const int r0 = h * 128 + l * 64;                                        \
                const char* src = (const char*)(gbase) +                                \
                    ((size_t)(r0 + srow) * K + (size_t)(t2) * 64) * 2 + schunk * 16;    \
                char* dst = &lds[(ldsoff) + (cbuf) * 32768 + (r0 + (wid << 3)) * 128];  \
                __builtin_amdgcn_global_load_lds(                                       \
                    (const __attribute__((address_space(1))) void*)src,                 \
                    (__attribute__((address_space(3))) void*)dst, 16, 0, 0);            \
            }                                                                           \
    }

#define LDA(cbuf, mh, mf, ks) \
    (*(const bf16x8*)&lds[(cbuf)*32768 + (wrow*128 + (mh)*64 + (mf)*16 + lq)*128 + ((((ks)*4 + lg)) ^ (lq & 7))*16])
#define LDB(cbuf, nh, nf, ks) \
    (*(const bf16x8*)&lds[65536 + (cbuf)*32768 + (wcol*64 + (nh)*32 + (nf)*16 + lq)*128 + ((((ks)*4 + lg)) ^ (lq & 7))*16])

    f32x4 acc[8][4] = {};
    bf16x8 a[4][2], b0[2][2], b1[2][2];

    STAGE_MAT(Ag, 0,     0, 0); STAGE_MAT(Bg, 65536, 0, 0);
    STAGE_MAT(Ag, 0,     1, 1); STAGE_MAT(Bg, 65536, 1, 1);
    asm volatile("s_waitcnt vmcnt(8)" ::: "memory");
    __builtin_amdgcn_s_barrier();

    for (int t = 0; t < nt; ++t) {
        const int cb = t & 1;
        const bool more = (t + 2) < nt;

        // ===== ph1: (mh0, nh0) =====
#pragma unroll
        for (int mf = 0; mf < 4; ++mf) { a[mf][0] = LDA(cb, 0, mf, 0); a[mf][1] = LDA(cb, 0, mf, 1); }
#pragma unroll
        for (int nf = 0; nf < 2; ++nf) { b0[nf][0] = LDB(cb, 0, nf, 0); b0[nf][1] = LDB(cb, 0, nf, 1); }
        __builtin_amdgcn_s_barrier();
        __builtin_amdgcn_s_setprio(1);
#pragma unroll
        for (int mf = 0; mf < 4; ++mf)
#pragma unroll
            for (int nf = 0; nf < 2; ++nf)
#pragma unroll
                for (int ks = 0; ks < 2; ++ks)
                    acc[mf][nf] = mfma16(a[mf][ks], b0[nf][ks], acc[mf][nf]);
        __builtin_amdgcn_s_setprio(0);
        asm volatile("s_waitcnt lgkmcnt(0)" ::: "memory");
        __builtin_amdgcn_s_barrier();

        // ===== ph2: (mh0, nh1) =====
#pragma unroll
        for (int nf = 0; nf < 2; ++nf) { b1[nf][0] = LDB(cb, 1, nf, 0); b1[nf][1] = LDB(cb, 1, nf, 1); }
        __builtin_amdgcn_s_barrier();
        __builtin_amdgcn_s_setprio(1);
#pragma unroll
        for (int mf = 0; mf < 4; ++mf)
#pragma unroll
            for (int nf = 0; nf < 2; ++nf)
#pragma unroll
                for (int ks = 0; ks < 2; ++ks)
                    acc[mf][2 + nf] = mfma16(a[mf][ks], b1[nf][ks], acc[mf][2 + nf]);
        __builtin_amdgcn_s_setprio(0);
        asm volatile("s_waitcnt lgkmcnt(0)" ::: "memory");
        __builtin_amdgcn_s_barrier();

        // ===== ph3: (mh1, nh1); stage B(t+2) =====
#pragma unroll
        for (int mf = 0; mf < 4; ++mf) { a[mf][0] = LDA(cb, 1, mf, 0); a[mf][1] = LDA(cb, 1, mf, 1); }
        if (more) STAGE_MAT(Bg, 65536, t + 2, cb);
        __builtin_amdgcn_s_barrier();
        __builtin_amdgcn_s_setprio(1);
#pragma unroll
        for (int mf = 0; mf < 4; ++mf)
#pragma unroll
            for (int nf = 0; nf < 2; ++nf)
#pragma unroll
                for (int ks = 0; ks < 2; ++ks)
                    acc[4 + mf][2 + nf] = mfma16(a[mf][ks], b1[nf][ks], acc[4 + mf][2 + nf]);
        __builtin_amdgcn_s_setprio(0);
        asm volatile("s_waitcnt lgkmcnt(0)" ::: "memory");
        __builtin_amdgcn_s_barrier();

        // ===== ph4: (mh1, nh0); stage A(t+2) =====
        if (more) STAGE_MAT(Ag, 0, t + 2, cb);
        __builtin_amdgcn_s_barrier();
        __builtin_amdgcn_s_setprio(1);
#pragma unroll
        for (int mf = 0; mf < 4; ++mf)
#pragma unroll
            for (int nf = 0; nf < 2; ++nf)
#pragma unroll
                for (int ks = 0; ks < 2; ++ks)
                    acc[4 + mf][nf] = mfma16(a[mf][ks], b0[nf][ks], acc[4 + mf][nf]);
        __builtin_amdgcn_s_setprio(0);
        if (t < nt - 1) {
            if (t == nt - 2) asm volatile("s_waitcnt vmcnt(0) lgkmcnt(0)" ::: "memory");
            else             asm volatile("s_waitcnt vmcnt(8) lgkmcnt(0)" ::: "memory");
            __builtin_amdgcn_s_barrier();
        }
    }
#undef STAGE_MAT
#undef LDA
#undef LDB

#pragma unroll
    for (int mf = 0; mf < 8; ++mf)
#pragma unroll
        for (int nf = 0; nf < 4; ++nf)
#pragma unroll
            for (int r = 0; r < 4; ++r) {
                int row = brow + wrow * 128 + mf * 16 + lg * 4 + r;
                int col = bcol + wcol * 64 + nf * 16 + lq;
                store_out(&C[(size_t)row * N + col], acc[mf][nf][r]);
            }
}

// ---------------- RoPE for q or k (optional pre-scale folded in) ----------------
__global__ __launch_bounds__(256) void rope_qk(const bf16* __restrict__ qkv,
                                               bf16* __restrict__ outp,
                                               int nheads, int col_off, float qscale) {
    size_t idx = (size_t)blockIdx.x * 256 + threadIdx.x;  // (b,h,t,i) i<64
    int i = (int)(idx & 63);
    size_t rest = idx >> 6;
    int t = (int)(rest % T_);
    rest /= T_;
    int hh = (int)(rest % nheads);
    int b = (int)(rest / nheads);

    const bf16* src = qkv + (size_t)(b * T_ + t) * QKVN_ + col_off + hh * HD_;
    float x0 = __bfloat162float(src[i]);
    float x1 = __bfloat162float(src[i + 64]);
    float inv = exp2f((float)i * -0.20762050593045952f);
    float th = (float)t * inv;
    float s = sinf(th), c = cosf(th);
    bf16* dst = outp + ((size_t)(b * nheads + hh) * T_ + t) * HD_;
    dst[i]      = __float2bfloat16((x0 * c - x1 * s) * qscale);
    dst[i + 64] = __float2bfloat16((x1 * c + x0 * s) * qscale);
}

// ---------------- V transpose: qkv v-slice [B,T,NKV,HD] -> vt [B,NKV,HD,T] ----------------
__global__ __launch_bounds__(256) void vtrans(const bf16* __restrict__ qkv,
                                              bf16* __restrict__ vt) {
    __shared__ bf16 tile[32][33];
    int gx = blockIdx.x;               // [b(1)|kv(3)|tt(6)|dt(2)]
    int dt = gx & 3;
    int tt = (gx >> 2) & 63;
    int kv = (gx >> 8) & 7;
    int b  = gx >> 11;
    int d0 = dt * 32, t0 = tt * 32;
    int tx = threadIdx.x & 31, ty = threadIdx.x >> 5;

    const bf16* src = qkv + (size_t)(b * T_ + t0) * QKVN_ + (NH_*HD_ + NKV_*HD_) + kv * HD_ + d0;
#pragma unroll
    for (int p = 0; p < 4; ++p)
        tile[p*8 + ty][tx] = src[(size_t)(p*8 + ty) * QKVN_ + tx];
    __syncthreads();
    bf16* dst = vt + ((size_t)((b * NKV_ + kv) * HD_ + d0)) * T_ + t0;
#pragma unroll
    for (int p = 0; p < 4; ++p)
        dst[(size_t)(p*8 + ty) * T_ + tx] = tile[tx][p*8 + ty];
}

// ---------------- Flash attention (causal, GQA), pipelined ----------------
// Q [B,NH,T,HD] (pre-scaled), K [B,NKV,T,HD], VT [B,NKV,HD,T] -> O [B,T,NH,HD]
// 2048 blocks; kv = lin&7 keeps each kv-head's K/V on one XCD L2.
// Per wave: 16 q rows, KV tile = 64 keys. Whole K-tile in regs, prefetched
// cross-tile; V issued early (softmax covers latency); defer-max (THR=8).
__global__ __launch_bounds__(256, 2) void fattn(const bf16* __restrict__ Q,
                                                const bf16* __restrict__ Kt,
                                                const bf16* __restrict__ VT,
                                                bf16* __restrict__ O) {
    const int lin = blockIdx.x;
    const int grp = lin & 15;          // (b,kv)
    const int kv = grp & 7, b = grp >> 3;
    const int idx = lin >> 4;          // 0..127
    const int h  = kv * 4 + (idx & 3); // GROUPS=4
    const int qb = 31 - (idx >> 2);    // heavy blocks first

    const int tid = threadIdx.x, wid = tid >> 6, lane = tid & 63;
    const int lq = lane & 15, lg = lane >> 4;
    const int q0 = qb * 64 + wid * 16;   // this wave's 16 q rows

    const bf16* Qp = Q + ((size_t)(b * NH_ + h) * T_ + q0) * HD_;
    bf16x8 qf[4];
#pragma unroll
    for (int c = 0; c < 4; ++c)
        qf[c] = *(const bf16x8*)&Qp[(size_t)lq * HD_ + c * 32 + lg * 8];

    const bf16* Kp = Kt + (size_t)(b * NKV_ + kv) * T_ * HD_;
    const bf16* Vp = VT + (size_t)(b * NKV_ + kv) * HD_ * T_;

    f32x4 oacc[8] = {};
    float m_r[4], l_r[4];
#pragma unroll
    for (int r = 0; r < 4; ++r) { m_r[r] = -INFINITY; l_r[r] = 0.f; }

    __shared__ __align__(16) bf16 p_lds[4][16][72];

    const int kv_end = q0 + 16;   // per-wave causal bound

    // prologue: K tile 0 into registers
    bf16x8 kf[4][4];
#pragma unroll
    for (int n = 0; n < 4; ++n)
#pragma unroll
        for (int c = 0; c < 4; ++c)
            kf[n][c] = *(const bf16x8*)&Kp[(size_t)(n*16 + lq) * HD_ + c * 32 + lg * 8];

    for (int t0 = 0; t0 < kv_end; t0 += 64) {
        // ---- early V issue (ks=0): lands under softmax ----
        bf16x8 vf0[8];
#pragma unroll
        for (int f = 0; f < 8; ++f)
            vf0[f] = *(const bf16x8*)&Vp[(size_t)(f*16 + lq) * T_ + t0 + lg * 8];

        // ---- S = Q @ K^T : 16 x 64 ----
        f32x4 s[4] = {};
        __builtin_amdgcn_s_setprio(1);
#pragma unroll
        for (int n = 0; n < 4; ++n)
#pragma unroll
            for (int c = 0; c < 4; ++c)
                s[n] = mfma16(qf[c], kf[n][c], s[n]);
        __builtin_amdgcn_s_setprio(0);

        // ---- prefetch K(t+1): covered by softmax + PV ----
        if (t0 + 64 < kv_end) {
#pragma unroll
            for (int n = 0; n < 4; ++n)
#pragma unroll
                for (int c = 0; c < 4; ++c)
                    kf[n][c] = *(const bf16x8*)&Kp[(size_t)(t0 + 64 + n*16 + lq) * HD_ + c * 32 + lg * 8];
        }

        // ---- causal mask (Q pre-scaled) ----
#pragma unroll
        for (int n = 0; n < 4; ++n)
#pragma unroll
            for (int r = 0; r < 4; ++r) {
                int kk = t0 + n*16 + lq;
                int qq = q0 + lg*4 + r;
                if (kk > qq) s[n][r] = -INFINITY;
            }

        // ---- online softmax with defer-max (THR=8) ----
        float rmax[4];
#pragma unroll
        for (int r = 0; r < 4; ++r) {
            rmax[r] = fmaxf(fmaxf(s[0][r], s[1][r]), fmaxf(s[2][r], s[3][r]));
#pragma unroll
            for (int off = 8; off >= 1; off >>= 1)
                rmax[r] = fmaxf(rmax[r], __shfl_xor(rmax[r], off));
        }
        float dmax = fmaxf(fmaxf(rmax[0] - m_r[0], rmax[1] - m_r[1]),
                           fmaxf(rmax[2] - m_r[2], rmax[3] - m_r[3]));
        if (__any(dmax > 8.0f)) {
#pragma unroll
            for (int r = 0; r < 4; ++r) {
                float mnew = fmaxf(m_r[r], rmax[r]);
                float alpha = __expf(m_r[r] - mnew);   // first tile: exp(-inf)=0
                m_r[r] = mnew;
                l_r[r] *= alpha;
#pragma unroll
                for (int f = 0; f < 8; ++f) oacc[f][r] *= alpha;
            }
        }
#pragma unroll
        for (int r = 0; r < 4; ++r) {
            float rsum = 0.f;
#pragma unroll
            for (int n = 0; n < 4; ++n) {
                float p = __expf(s[n][r] - m_r[r]);   // bounded by e^8
                s[n][r] = p;
                rsum += p;
            }
#pragma unroll
            for (int off = 8; off >= 1; off >>= 1)
                rsum += __shfl_xor(rsum, off);
            l_r[r] += rsum;
        }

        // ---- early V issue (ks=1): lands under P->LDS + PV ks0 ----
        bf16x8 vf1[8];
#pragma unroll
        for (int f = 0; f < 8; ++f)
            vf1[f] = *(const bf16x8*)&Vp[(size_t)(f*16 + lq) * T_ + t0 + 32 + lg * 8];

        // ---- P -> LDS -> A-fragments ----
#pragma unroll
        for (int n = 0; n < 4; ++n)
#pragma unroll
            for (int r = 0; r < 4; ++r)
                p_lds[wid][lg*4 + r][n*16 + lq] = __float2bfloat16(s[n][r]);
        bf16x8 pa0 = *(const bf16x8*)&p_lds[wid][lq][lg * 8];
        bf16x8 pa1 = *(const bf16x8*)&p_lds[wid][lq][32 + lg * 8];

        // ---- O += P @ V ----
        __builtin_amdgcn_s_setprio(1);
#pragma unroll
        for (int f = 0; f < 8; ++f) oacc[f] = mfma16(pa0, vf0[f], oacc[f]);
#pragma unroll
        for (int f = 0; f < 8; ++f) oacc[f] = mfma16(pa1, vf1[f], oacc[f]);
        __builtin_amdgcn_s_setprio(0);
    }

    // ---- epilogue: divide by l, store [B,T,NH,HD] ----
#pragma unroll
    for (int f = 0; f < 8; ++f)
#pragma unroll
        for (int r = 0; r < 4; ++r) {
            int row = q0 + lg*4 + r;
            int d = f*16 + lq;
            float v = oacc[f][r] / l_r[r];
            O[((size_t)(b * T_ + row) * NH_ + h) * HD_ + d] = __float2bfloat16(v);
        }
}

// ---------------- launch ----------------
extern "C" void kernel_launch(void* const* d_in, const int* in_sizes, int n_in,
                              void* d_out, int out_size, void* d_ws, size_t ws_size,
                              hipStream_t stream) {
    const float* x  = (const float*)d_in[0];
    const float* wq = (const float*)d_in[1];
    const float* wk = (const float*)d_in[2];
    const float* wv = (const float*)d_in[3];
    const float* wo = (const float*)d_in[4];
    float* out = (float*)d_out;

    bf16* ws    = (bf16*)d_ws;
    bf16* xb    = ws;
    bf16* wqkvT = xb + (size_t)M_ * C_;
    bf16* woT   = wqkvT + (size_t)QKVN_ * C_;
    bf16* qkv   = woT + (size_t)C_ * C_;

    bf16* attn = xb;                                  // reuse after QKV GEMM
    bf16* q_r  = wqkvT;                               // reuse after QKV GEMM
    bf16* k_r  = q_r + (size_t)B_ * NH_ * T_ * HD_;
    bf16* vt   = k_r + (size_t)B_ * NKV_ * T_ * HD_;

    // 1) casts / transposes
    cast_f32_bf16<<<(M_ * C_ / 4 + 255) / 256, 256, 0, stream>>>(x, xb, M_ * C_ / 4);
    transpose_cast<<<dim3(128, 128), 256, 0, stream>>>(wq, wqkvT, C_, NH_ * HD_);
    transpose_cast<<<dim3(32, 128), 256, 0, stream>>>(wk, wqkvT + (size_t)(NH_ * HD_) * C_, C_, NKV_ * HD_);
    transpose_cast<<<dim3(32, 128), 256, 0, stream>>>(wv, wqkvT + (size_t)(NH_ * HD_ + NKV_ * HD_) * C_, C_, NKV_ * HD_);
    transpose_cast<<<dim3(128, 128), 256, 0, stream>>>(wo, woT, NH_ * HD_, C_);

    // 2) fused QKV GEMM
    gemm256<bf16><<<dim3((QKVN_ / 256) * (M_ / 256)), 512, 0, stream>>>(xb, wqkvT, qkv, M_, QKVN_, C_);

    // 3) RoPE (Q pre-scaled by 1/sqrt(HD)) + layout transforms
    rope_qk<<<(B_ * NH_ * T_ * 64) / 256, 256, 0, stream>>>(qkv, q_r, NH_, 0, 0.08838834764831843f);
    rope_qk<<<(B_ * NKV_ * T_ * 64) / 256, 256, 0, stream>>>(qkv, k_r, NKV_, NH_ * HD_, 1.0f);
    vtrans<<<B_ * NKV_ * (T_ / 32) * (HD_ / 32), 256, 0, stream>>>(qkv, vt);

    // 4) attention (2048 blocks)
    fattn<<<dim3(32 * 4 * NKV_ * B_), 256, 0, stream>>>(q_r, k_r, vt, attn);

    // 5) output projection
    gemm256<float><<<dim3((C_ / 256) * (M_ / 256)), 512, 0, stream>>>(attn, woT, out, M_, C_, C_);
}

// Round 5
// 776.899 us; speedup vs baseline: 1.1881x; 1.1881x over previous
//
#include <hip/hip_runtime.h>
#include <hip/hip_bf16.h>
#include <math.h>

#define B_ 2
#define T_ 2048
#define C_ 4096
#define NH_ 32
#define NKV_ 8
#define HD_ 128
#define M_ (B_*T_)              // 4096 rows
#define QKVN_ (NH_*HD_ + 2*NKV_*HD_)  // 6144

using bf16 = __hip_bfloat16;
typedef __bf16 bf16x8 __attribute__((ext_vector_type(8)));
typedef float f32x4 __attribute__((ext_vector_type(4)));

__device__ inline f32x4 mfma16(bf16x8 a, bf16x8 b, f32x4 c) {
    return __builtin_amdgcn_mfma_f32_16x16x32_bf16(a, b, c, 0, 0, 0);
}

// ---------------- cast f32 -> bf16 (vectorized x4) ----------------
__global__ __launch_bounds__(256) void cast_f32_bf16(const float* __restrict__ in,
                                                     bf16* __restrict__ out, int n4) {
    int i = blockIdx.x * 256 + threadIdx.x;
    if (i >= n4) return;
    float4 v = reinterpret_cast<const float4*>(in)[i];
    union { bf16 h[4]; uint2 u; } o;
    o.h[0] = __float2bfloat16(v.x);
    o.h[1] = __float2bfloat16(v.y);
    o.h[2] = __float2bfloat16(v.z);
    o.h[3] = __float2bfloat16(v.w);
    reinterpret_cast<uint2*>(out)[i] = o.u;
}

// ---------------- transpose + cast: in f32 [K][N] -> out bf16 [N][K] ----------------
__global__ __launch_bounds__(256) void transpose_cast(const float* __restrict__ in,
                                                      bf16* __restrict__ out, int K, int N) {
    __shared__ float tile[32][33];
    int tx = threadIdx.x & 31, ty = threadIdx.x >> 5;  // 32 x 8
    int n0 = blockIdx.x << 5, k0 = blockIdx.y << 5;
#pragma unroll
    for (int p = 0; p < 4; ++p)
        tile[p*8 + ty][tx] = in[(size_t)(k0 + p*8 + ty) * N + n0 + tx];
    __syncthreads();
#pragma unroll
    for (int p = 0; p < 4; ++p)
        out[(size_t)(n0 + p*8 + ty) * K + k0 + tx] = __float2bfloat16(tile[tx][p*8 + ty]);
}

// ---------------- 256x256 deep-pipelined GEMM ----------------
__device__ inline void store_out(float* p, float v) { *p = v; }
__device__ inline void store_out(bf16*  p, float v) { *p = __float2bfloat16(v); }

template <typename OutT>
__global__ __launch_bounds__(512, 2) void gemm256(const bf16* __restrict__ A,
                                                  const bf16* __restrict__ Bt,
                                                  OutT* __restrict__ C,
                                                  int M, int N, int K) {
    __shared__ __align__(16) char lds[131072];   // A: [0,64K) B: [64K,128K); each [buf][256][128B]
    const int tid = threadIdx.x;
    const int wid = tid >> 6, lane = tid & 63;
    const int lq = lane & 15, lg = lane >> 4;
    const int wrow = wid >> 2, wcol = wid & 3;

    // XCD chunk swizzle (nwg % 8 == 0)
    const int nwg = gridDim.x;
    const int q8 = nwg >> 3;
    const int wg = (blockIdx.x & 7) * q8 + (blockIdx.x >> 3);
    const int nby = M >> 8;
    const int by = wg % nby, bx = wg / nby;
    const int brow = by << 8, bcol = bx << 8;

    const bf16* Ag = A + (size_t)brow * K;
    const bf16* Bg = Bt + (size_t)bcol * K;
    const int nt = K >> 6;

    const int srow = (wid << 3) + (lane >> 3);              // 0..63 within a 64-row group
    const int schunk = (lane & 7) ^ ((lane >> 3) & 7);      // inverse-swizzle on SOURCE

#define STAGE_MAT(gbase, ldsoff, t2, cbuf)                                              \
    {                                                                                   \
        _Pragma("unroll")                                                               \
        for (int h = 0; h < 2; ++h)                                                     \
            _Pragma("unroll")                                                           \
            for (int l = 0; l < 2; ++l) {                                               \
                const int r0 = h * 128 + l * 64;                                        \
                const char* src = (const char*)(gbase) +                                \
                    ((size_t)(r0 + srow) * K + (size_t)(t2) * 64) * 2 + schunk * 16;    \
                char* dst = &lds[(ldsoff) + (cbuf) * 32768 + (r0 + (wid << 3)) * 128];  \
                __builtin_amdgcn_global_load_lds(                                       \
                    (const __attribute__((address_space(1))) void*)src,                 \
                    (__attribute__((address_space(3))) void*)dst, 16, 0, 0);            \
            }                                                                           \
    }

#define LDA(cbuf, mh, mf, ks) \
    (*(const bf16x8*)&lds[(cbuf)*32768 + (wrow*128 + (mh)*64 + (mf)*16 + lq)*128 + ((((ks)*4 + lg)) ^ (lq & 7))*16])
#define LDB(cbuf, nh, nf, ks) \
    (*(const bf16x8*)&lds[65536 + (cbuf)*32768 + (wcol*64 + (nh)*32 + (nf)*16 + lq)*128 + ((((ks)*4 + lg)) ^ (lq & 7))*16])

    f32x4 acc[8][4] = {};
    bf16x8 a[4][2], b0[2][2], b1[2][2];

    STAGE_MAT(Ag, 0,     0, 0); STAGE_MAT(Bg, 65536, 0, 0);
    STAGE_MAT(Ag, 0,     1, 1); STAGE_MAT(Bg, 65536, 1, 1);
    asm volatile("s_waitcnt vmcnt(8)" ::: "memory");
    __builtin_amdgcn_s_barrier();

    for (int t = 0; t < nt; ++t) {
        const int cb = t & 1;
        const bool more = (t + 2) < nt;

        // ===== ph1: (mh0, nh0) =====
#pragma unroll
        for (int mf = 0; mf < 4; ++mf) { a[mf][0] = LDA(cb, 0, mf, 0); a[mf][1] = LDA(cb, 0, mf, 1); }
#pragma unroll
        for (int nf = 0; nf < 2; ++nf) { b0[nf][0] = LDB(cb, 0, nf, 0); b0[nf][1] = LDB(cb, 0, nf, 1); }
        __builtin_amdgcn_s_barrier();
        __builtin_amdgcn_s_setprio(1);
#pragma unroll
        for (int mf = 0; mf < 4; ++mf)
#pragma unroll
            for (int nf = 0; nf < 2; ++nf)
#pragma unroll
                for (int ks = 0; ks < 2; ++ks)
                    acc[mf][nf] = mfma16(a[mf][ks], b0[nf][ks], acc[mf][nf]);
        __builtin_amdgcn_s_setprio(0);
        asm volatile("s_waitcnt lgkmcnt(0)" ::: "memory");
        __builtin_amdgcn_s_barrier();

        // ===== ph2: (mh0, nh1) =====
#pragma unroll
        for (int nf = 0; nf < 2; ++nf) { b1[nf][0] = LDB(cb, 1, nf, 0); b1[nf][1] = LDB(cb, 1, nf, 1); }
        __builtin_amdgcn_s_barrier();
        __builtin_amdgcn_s_setprio(1);
#pragma unroll
        for (int mf = 0; mf < 4; ++mf)
#pragma unroll
            for (int nf = 0; nf < 2; ++nf)
#pragma unroll
                for (int ks = 0; ks < 2; ++ks)
                    acc[mf][2 + nf] = mfma16(a[mf][ks], b1[nf][ks], acc[mf][2 + nf]);
        __builtin_amdgcn_s_setprio(0);
        asm volatile("s_waitcnt lgkmcnt(0)" ::: "memory");
        __builtin_amdgcn_s_barrier();

        // ===== ph3: (mh1, nh1); stage B(t+2) =====
#pragma unroll
        for (int mf = 0; mf < 4; ++mf) { a[mf][0] = LDA(cb, 1, mf, 0); a[mf][1] = LDA(cb, 1, mf, 1); }
        if (more) STAGE_MAT(Bg, 65536, t + 2, cb);
        __builtin_amdgcn_s_barrier();
        __builtin_amdgcn_s_setprio(1);
#pragma unroll
        for (int mf = 0; mf < 4; ++mf)
#pragma unroll
            for (int nf = 0; nf < 2; ++nf)
#pragma unroll
                for (int ks = 0; ks < 2; ++ks)
                    acc[4 + mf][2 + nf] = mfma16(a[mf][ks], b1[nf][ks], acc[4 + mf][2 + nf]);
        __builtin_amdgcn_s_setprio(0);
        asm volatile("s_waitcnt lgkmcnt(0)" ::: "memory");
        __builtin_amdgcn_s_barrier();

        // ===== ph4: (mh1, nh0); stage A(t+2) =====
        if (more) STAGE_MAT(Ag, 0, t + 2, cb);
        __builtin_amdgcn_s_barrier();
        __builtin_amdgcn_s_setprio(1);
#pragma unroll
        for (int mf = 0; mf < 4; ++mf)
#pragma unroll
            for (int nf = 0; nf < 2; ++nf)
#pragma unroll
                for (int ks = 0; ks < 2; ++ks)
                    acc[4 + mf][nf] = mfma16(a[mf][ks], b0[nf][ks], acc[4 + mf][nf]);
        __builtin_amdgcn_s_setprio(0);
        if (t < nt - 1) {
            if (t == nt - 2) asm volatile("s_waitcnt vmcnt(0) lgkmcnt(0)" ::: "memory");
            else             asm volatile("s_waitcnt vmcnt(8) lgkmcnt(0)" ::: "memory");
            __builtin_amdgcn_s_barrier();
        }
    }
#undef STAGE_MAT
#undef LDA
#undef LDB

#pragma unroll
    for (int mf = 0; mf < 8; ++mf)
#pragma unroll
        for (int nf = 0; nf < 4; ++nf)
#pragma unroll
            for (int r = 0; r < 4; ++r) {
                int row = brow + wrow * 128 + mf * 16 + lg * 4 + r;
                int col = bcol + wcol * 64 + nf * 16 + lq;
                store_out(&C[(size_t)row * N + col], acc[mf][nf][r]);
            }
}

// ---------------- RoPE for q or k (optional pre-scale folded in) ----------------
__global__ __launch_bounds__(256) void rope_qk(const bf16* __restrict__ qkv,
                                               bf16* __restrict__ outp,
                                               int nheads, int col_off, float qscale) {
    size_t idx = (size_t)blockIdx.x * 256 + threadIdx.x;  // (b,h,t,i) i<64
    int i = (int)(idx & 63);
    size_t rest = idx >> 6;
    int t = (int)(rest % T_);
    rest /= T_;
    int hh = (int)(rest % nheads);
    int b = (int)(rest / nheads);

    const bf16* src = qkv + (size_t)(b * T_ + t) * QKVN_ + col_off + hh * HD_;
    float x0 = __bfloat162float(src[i]);
    float x1 = __bfloat162float(src[i + 64]);
    float inv = exp2f((float)i * -0.20762050593045952f);
    float th = (float)t * inv;
    float s = sinf(th), c = cosf(th);
    bf16* dst = outp + ((size_t)(b * nheads + hh) * T_ + t) * HD_;
    dst[i]      = __float2bfloat16((x0 * c - x1 * s) * qscale);
    dst[i + 64] = __float2bfloat16((x1 * c + x0 * s) * qscale);
}

// ---------------- V transpose: qkv v-slice [B,T,NKV,HD] -> vt [B,NKV,HD,T] ----------------
__global__ __launch_bounds__(256) void vtrans(const bf16* __restrict__ qkv,
                                              bf16* __restrict__ vt) {
    __shared__ bf16 tile[32][33];
    int gx = blockIdx.x;               // [b(1)|kv(3)|tt(6)|dt(2)]
    int dt = gx & 3;
    int tt = (gx >> 2) & 63;
    int kv = (gx >> 8) & 7;
    int b  = gx >> 11;
    int d0 = dt * 32, t0 = tt * 32;
    int tx = threadIdx.x & 31, ty = threadIdx.x >> 5;

    const bf16* src = qkv + (size_t)(b * T_ + t0) * QKVN_ + (NH_*HD_ + NKV_*HD_) + kv * HD_ + d0;
#pragma unroll
    for (int p = 0; p < 4; ++p)
        tile[p*8 + ty][tx] = src[(size_t)(p*8 + ty) * QKVN_ + tx];
    __syncthreads();
    bf16* dst = vt + ((size_t)((b * NKV_ + kv) * HD_ + d0)) * T_ + t0;
#pragma unroll
    for (int p = 0; p < 4; ++p)
        dst[(size_t)(p*8 + ty) * T_ + tx] = tile[tx][p*8 + ty];
}

// ---------------- Flash attention (causal, GQA), load-balanced ----------------
// Q [B,NH,T,HD] (pre-scaled by HD^-0.5), K [B,NKV,T,HD], VT [B,NKV,HD,T] -> O [B,T,NH,HD]
// 512 blocks (= resident capacity at 2 waves/SIMD): each block runs q-tile jp
// then q-tile 15-jp (flash-2 causal pairing -> ~equal work per block, no tail).
// kv = lin&7 keeps each kv-head's K/V on one XCD's L2 (2 MB/XCD).
// Per wave: 32 q rows, KV tile = 64 keys; early V issue; defer-max (THR=8).
__global__ __launch_bounds__(256) void fattn(const bf16* __restrict__ Q,
                                             const bf16* __restrict__ Kt,
                                             const bf16* __restrict__ VT,
                                             bf16* __restrict__ O) {
    const int lin = blockIdx.x;          // 512 blocks
    const int kv = lin & 7;
    const int b  = (lin >> 3) & 1;
    const int idx = lin >> 4;            // 0..31
    const int h  = kv * 4 + (idx & 3);   // GROUPS=4
    const int jp = idx >> 2;             // 0..7 pair index

    const int tid = threadIdx.x, wid = tid >> 6, lane = tid & 63;
    const int lq = lane & 15, lg = lane >> 4;

    const bf16* Kp = Kt + (size_t)(b * NKV_ + kv) * T_ * HD_;
    const bf16* Vp = VT + (size_t)(b * NKV_ + kv) * HD_ * T_;

    __shared__ __align__(16) bf16 p_lds[4][32][72];

    for (int half = 0; half < 2; ++half) {
        const int qb = half ? (15 - jp) : jp;
        const int q0 = qb * 128 + wid * 32;   // this wave's 32 q rows

        const bf16* Qp = Q + ((size_t)(b * NH_ + h) * T_ + q0) * HD_;
        bf16x8 qf[2][4];
#pragma unroll
        for (int m = 0; m < 2; ++m)
#pragma unroll
            for (int c = 0; c < 4; ++c)
                qf[m][c] = *(const bf16x8*)&Qp[(size_t)(m*16 + lq) * HD_ + c * 32 + lg * 8];

        f32x4 oacc[2][8] = {};
        float m_r[2][4], l_r[2][4];
#pragma unroll
        for (int m = 0; m < 2; ++m)
#pragma unroll
            for (int r = 0; r < 4; ++r) { m_r[m][r] = -INFINITY; l_r[m][r] = 0.f; }

        const int kv_end = q0 + 32;   // per-wave causal bound

        for (int t0 = 0; t0 < kv_end; t0 += 64) {
            // ---- early V issue (ks=0): in flight during QK + softmax ----
            bf16x8 vf0[8];
#pragma unroll
            for (int f = 0; f < 8; ++f)
                vf0[f] = *(const bf16x8*)&Vp[(size_t)(f*16 + lq) * T_ + t0 + lg * 8];

            // ---- S = Q @ K^T : 32 x 64 ----
            f32x4 s[2][4] = {};
#pragma unroll
            for (int n = 0; n < 4; ++n) {
                bf16x8 kf[4];
#pragma unroll
                for (int c = 0; c < 4; ++c)
                    kf[c] = *(const bf16x8*)&Kp[(size_t)(t0 + n*16 + lq) * HD_ + c * 32 + lg * 8];
                __builtin_amdgcn_s_setprio(1);
#pragma unroll
                for (int c = 0; c < 4; ++c) {
                    s[0][n] = mfma16(qf[0][c], kf[c], s[0][n]);
                    s[1][n] = mfma16(qf[1][c], kf[c], s[1][n]);
                }
                __builtin_amdgcn_s_setprio(0);
            }

            // ---- causal mask (Q pre-scaled) ----
#pragma unroll
            for (int m = 0; m < 2; ++m)
#pragma unroll
                for (int n = 0; n < 4; ++n)
#pragma unroll
                    for (int r = 0; r < 4; ++r) {
                        int kk = t0 + n*16 + lq;
                        int qq = q0 + m*16 + lg*4 + r;
                        if (kk > qq) s[m][n][r] = -INFINITY;
                    }

            // ---- row max + defer-max (THR=8) ----
            float rmax[2][4];
#pragma unroll
            for (int m = 0; m < 2; ++m)
#pragma unroll
                for (int r = 0; r < 4; ++r) {
                    float v = fmaxf(fmaxf(s[m][0][r], s[m][1][r]),
                                    fmaxf(s[m][2][r], s[m][3][r]));
#pragma unroll
                    for (int off = 8; off >= 1; off >>= 1)
                        v = fmaxf(v, __shfl_xor(v, off));
                    rmax[m][r] = v;
                }
            float dmax = -INFINITY;
#pragma unroll
            for (int m = 0; m < 2; ++m)
#pragma unroll
                for (int r = 0; r < 4; ++r)
                    dmax = fmaxf(dmax, rmax[m][r] - m_r[m][r]);
            if (__any(dmax > 8.0f)) {
#pragma unroll
                for (int m = 0; m < 2; ++m)
#pragma unroll
                    for (int r = 0; r < 4; ++r) {
                        float mnew = fmaxf(m_r[m][r], rmax[m][r]);
                        float alpha = __expf(m_r[m][r] - mnew);   // first tile: exp(-inf)=0
                        m_r[m][r] = mnew;
                        l_r[m][r] *= alpha;
#pragma unroll
                        for (int f = 0; f < 8; ++f) oacc[m][f][r] *= alpha;
                    }
            }

            // ---- exp + row sum ----
#pragma unroll
            for (int m = 0; m < 2; ++m)
#pragma unroll
                for (int r = 0; r < 4; ++r) {
                    float rsum = 0.f;
#pragma unroll
                    for (int n = 0; n < 4; ++n) {
                        float p = __expf(s[m][n][r] - m_r[m][r]);   // bounded by e^8
                        s[m][n][r] = p;
                        rsum += p;
                    }
#pragma unroll
                    for (int off = 8; off >= 1; off >>= 1)
                        rsum += __shfl_xor(rsum, off);
                    l_r[m][r] += rsum;
                }

            // ---- early V issue (ks=1): lands under P->LDS pack ----
            bf16x8 vf1[8];
#pragma unroll
            for (int f = 0; f < 8; ++f)
                vf1[f] = *(const bf16x8*)&Vp[(size_t)(f*16 + lq) * T_ + t0 + 32 + lg * 8];

            // ---- P -> LDS -> A-fragments ----
#pragma unroll
            for (int m = 0; m < 2; ++m)
#pragma unroll
                for (int n = 0; n < 4; ++n)
#pragma unroll
                    for (int r = 0; r < 4; ++r)
                        p_lds[wid][m*16 + lg*4 + r][n*16 + lq] = __float2bfloat16(s[m][n][r]);
            bf16x8 pa00 = *(const bf16x8*)&p_lds[wid][lq]     [lg * 8];
            bf16x8 pa10 = *(const bf16x8*)&p_lds[wid][16 + lq][lg * 8];

            // ---- O += P @ V (ks=0 then ks=1) ----
            __builtin_amdgcn_s_setprio(1);
#pragma unroll
            for (int f = 0; f < 8; ++f) {
                oacc[0][f] = mfma16(pa00, vf0[f], oacc[0][f]);
                oacc[1][f] = mfma16(pa10, vf0[f], oacc[1][f]);
            }
            __builtin_amdgcn_s_setprio(0);
            bf16x8 pa01 = *(const bf16x8*)&p_lds[wid][lq]     [32 + lg * 8];
            bf16x8 pa11 = *(const bf16x8*)&p_lds[wid][16 + lq][32 + lg * 8];
            __builtin_amdgcn_s_setprio(1);
#pragma unroll
            for (int f = 0; f < 8; ++f) {
                oacc[0][f] = mfma16(pa01, vf1[f], oacc[0][f]);
                oacc[1][f] = mfma16(pa11, vf1[f], oacc[1][f]);
            }
            __builtin_amdgcn_s_setprio(0);
        }

        // ---- epilogue: divide by l, store [B,T,NH,HD] ----
#pragma unroll
        for (int m = 0; m < 2; ++m)
#pragma unroll
            for (int f = 0; f < 8; ++f)
#pragma unroll
                for (int r = 0; r < 4; ++r) {
                    int row = q0 + m*16 + lg*4 + r;
                    int d = f*16 + lq;
                    float v = oacc[m][f][r] / l_r[m][r];
                    O[((size_t)(b * T_ + row) * NH_ + h) * HD_ + d] = __float2bfloat16(v);
                }
    }
}

// ---------------- launch ----------------
extern "C" void kernel_launch(void* const* d_in, const int* in_sizes, int n_in,
                              void* d_out, int out_size, void* d_ws, size_t ws_size,
                              hipStream_t stream) {
    const float* x  = (const float*)d_in[0];
    const float* wq = (const float*)d_in[1];
    const float* wk = (const float*)d_in[2];
    const float* wv = (const float*)d_in[3];
    const float* wo = (const float*)d_in[4];
    float* out = (float*)d_out;

    bf16* ws    = (bf16*)d_ws;
    bf16* xb    = ws;
    bf16* wqkvT = xb + (size_t)M_ * C_;
    bf16* woT   = wqkvT + (size_t)QKVN_ * C_;
    bf16* qkv   = woT + (size_t)C_ * C_;

    bf16* attn = xb;                                  // reuse after QKV GEMM
    bf16* q_r  = wqkvT;                               // reuse after QKV GEMM
    bf16* k_r  = q_r + (size_t)B_ * NH_ * T_ * HD_;
    bf16* vt   = k_r + (size_t)B_ * NKV_ * T_ * HD_;

    // 1) casts / transposes
    cast_f32_bf16<<<(M_ * C_ / 4 + 255) / 256, 256, 0, stream>>>(x, xb, M_ * C_ / 4);
    transpose_cast<<<dim3(128, 128), 256, 0, stream>>>(wq, wqkvT, C_, NH_ * HD_);
    transpose_cast<<<dim3(32, 128), 256, 0, stream>>>(wk, wqkvT + (size_t)(NH_ * HD_) * C_, C_, NKV_ * HD_);
    transpose_cast<<<dim3(32, 128), 256, 0, stream>>>(wv, wqkvT + (size_t)(NH_ * HD_ + NKV_ * HD_) * C_, C_, NKV_ * HD_);
    transpose_cast<<<dim3(128, 128), 256, 0, stream>>>(wo, woT, NH_ * HD_, C_);

    // 2) fused QKV GEMM
    gemm256<bf16><<<dim3((QKVN_ / 256) * (M_ / 256)), 512, 0, stream>>>(xb, wqkvT, qkv, M_, QKVN_, C_);

    // 3) RoPE (Q pre-scaled by 1/sqrt(HD)) + layout transforms
    rope_qk<<<(B_ * NH_ * T_ * 64) / 256, 256, 0, stream>>>(qkv, q_r, NH_, 0, 0.08838834764831843f);
    rope_qk<<<(B_ * NKV_ * T_ * 64) / 256, 256, 0, stream>>>(qkv, k_r, NKV_, NH_ * HD_, 1.0f);
    vtrans<<<B_ * NKV_ * (T_ / 32) * (HD_ / 32), 256, 0, stream>>>(qkv, vt);

    // 4) attention (512 balanced blocks)
    fattn<<<dim3(512), 256, 0, stream>>>(q_r, k_r, vt, attn);

    // 5) output projection
    gemm256<float><<<dim3((C_ / 256) * (M_ / 256)), 512, 0, stream>>>(attn, woT, out, M_, C_, C_);
}

// Round 6
// 701.278 us; speedup vs baseline: 1.3162x; 1.1078x over previous
//
#include <hip/hip_runtime.h>
#include <hip/hip_bf16.h>
#include <math.h>

#define B_ 2
#define T_ 2048
#define C_ 4096
#define NH_ 32
#define NKV_ 8
#define HD_ 128
#define M_ (B_*T_)              // 4096 rows
#define QKVN_ (NH_*HD_ + 2*NKV_*HD_)  // 6144

using bf16 = __hip_bfloat16;
typedef __bf16 bf16x8 __attribute__((ext_vector_type(8)));
typedef float f32x4 __attribute__((ext_vector_type(4)));

__device__ inline f32x4 mfma16(bf16x8 a, bf16x8 b, f32x4 c) {
    return __builtin_amdgcn_mfma_f32_16x16x32_bf16(a, b, c, 0, 0, 0);
}

// ---------------- cast f32 -> bf16 (vectorized x4) ----------------
__global__ __launch_bounds__(256) void cast_f32_bf16(const float* __restrict__ in,
                                                     bf16* __restrict__ out, int n4) {
    int i = blockIdx.x * 256 + threadIdx.x;
    if (i >= n4) return;
    float4 v = reinterpret_cast<const float4*>(in)[i];
    union { bf16 h[4]; uint2 u; } o;
    o.h[0] = __float2bfloat16(v.x);
    o.h[1] = __float2bfloat16(v.y);
    o.h[2] = __float2bfloat16(v.z);
    o.h[3] = __float2bfloat16(v.w);
    reinterpret_cast<uint2*>(out)[i] = o.u;
}

// ---------------- transpose + cast: in f32 [K][N] -> out bf16 [N][K] ----------------
__global__ __launch_bounds__(256) void transpose_cast(const float* __restrict__ in,
                                                      bf16* __restrict__ out, int K, int N) {
    __shared__ float tile[32][33];
    int tx = threadIdx.x & 31, ty = threadIdx.x >> 5;  // 32 x 8
    int n0 = blockIdx.x << 5, k0 = blockIdx.y << 5;
#pragma unroll
    for (int p = 0; p < 4; ++p)
        tile[p*8 + ty][tx] = in[(size_t)(k0 + p*8 + ty) * N + n0 + tx];
    __syncthreads();
#pragma unroll
    for (int p = 0; p < 4; ++p)
        out[(size_t)(n0 + p*8 + ty) * K + k0 + tx] = __float2bfloat16(tile[tx][p*8 + ty]);
}

// ---------------- 256x256 deep-pipelined GEMM ----------------
__device__ inline void store_out(float* p, float v) { *p = v; }
__device__ inline void store_out(bf16*  p, float v) { *p = __float2bfloat16(v); }

template <typename OutT>
__global__ __launch_bounds__(512, 2) void gemm256(const bf16* __restrict__ A,
                                                  const bf16* __restrict__ Bt,
                                                  OutT* __restrict__ C,
                                                  int M, int N, int K) {
    __shared__ __align__(16) char lds[131072];   // A: [0,64K) B: [64K,128K); each [buf][256][128B]
    const int tid = threadIdx.x;
    const int wid = tid >> 6, lane = tid & 63;
    const int lq = lane & 15, lg = lane >> 4;
    const int wrow = wid >> 2, wcol = wid & 3;

    // XCD chunk swizzle (nwg % 8 == 0)
    const int nwg = gridDim.x;
    const int q8 = nwg >> 3;
    const int wg = (blockIdx.x & 7) * q8 + (blockIdx.x >> 3);
    const int nby = M >> 8;
    const int by = wg % nby, bx = wg / nby;
    const int brow = by << 8, bcol = bx << 8;

    const bf16* Ag = A + (size_t)brow * K;
    const bf16* Bg = Bt + (size_t)bcol * K;
    const int nt = K >> 6;

    const int srow = (wid << 3) + (lane >> 3);              // 0..63 within a 64-row group
    const int schunk = (lane & 7) ^ ((lane >> 3) & 7);      // inverse-swizzle on SOURCE

#define STAGE_MAT(gbase, ldsoff, t2, cbuf)                                              \
    {                                                                                   \
        _Pragma("unroll")                                                               \
        for (int h = 0; h < 2; ++h)                                                     \
            _Pragma("unroll")                                                           \
            for (int l = 0; l < 2; ++l) {                                               \
                const int r0 = h * 128 + l * 64;                                        \
                const char* src = (const char*)(gbase) +                                \
                    ((size_t)(r0 + srow) * K + (size_t)(t2) * 64) * 2 + schunk * 16;    \
                char* dst = &lds[(ldsoff) + (cbuf) * 32768 + (r0 + (wid << 3)) * 128];  \
                __builtin_amdgcn_global_load_lds(                                       \
                    (const __attribute__((address_space(1))) void*)src,                 \
                    (__attribute__((address_space(3))) void*)dst, 16, 0, 0);            \
            }                                                                           \
    }

#define LDA(cbuf, mh, mf, ks) \
    (*(const bf16x8*)&lds[(cbuf)*32768 + (wrow*128 + (mh)*64 + (mf)*16 + lq)*128 + ((((ks)*4 + lg)) ^ (lq & 7))*16])
#define LDB(cbuf, nh, nf, ks) \
    (*(const bf16x8*)&lds[65536 + (cbuf)*32768 + (wcol*64 + (nh)*32 + (nf)*16 + lq)*128 + ((((ks)*4 + lg)) ^ (lq & 7))*16])

    f32x4 acc[8][4] = {};
    bf16x8 a[4][2], b0[2][2], b1[2][2];

    STAGE_MAT(Ag, 0,     0, 0); STAGE_MAT(Bg, 65536, 0, 0);
    STAGE_MAT(Ag, 0,     1, 1); STAGE_MAT(Bg, 65536, 1, 1);
    asm volatile("s_waitcnt vmcnt(8)" ::: "memory");
    __builtin_amdgcn_s_barrier();

    for (int t = 0; t < nt; ++t) {
        const int cb = t & 1;
        const bool more = (t + 2) < nt;

        // ===== ph1: (mh0, nh0) =====
#pragma unroll
        for (int mf = 0; mf < 4; ++mf) { a[mf][0] = LDA(cb, 0, mf, 0); a[mf][1] = LDA(cb, 0, mf, 1); }
#pragma unroll
        for (int nf = 0; nf < 2; ++nf) { b0[nf][0] = LDB(cb, 0, nf, 0); b0[nf][1] = LDB(cb, 0, nf, 1); }
        __builtin_amdgcn_s_barrier();
        __builtin_amdgcn_s_setprio(1);
#pragma unroll
        for (int mf = 0; mf < 4; ++mf)
#pragma unroll
            for (int nf = 0; nf < 2; ++nf)
#pragma unroll
                for (int ks = 0; ks < 2; ++ks)
                    acc[mf][nf] = mfma16(a[mf][ks], b0[nf][ks], acc[mf][nf]);
        __builtin_amdgcn_s_setprio(0);
        asm volatile("s_waitcnt lgkmcnt(0)" ::: "memory");
        __builtin_amdgcn_s_barrier();

        // ===== ph2: (mh0, nh1) =====
#pragma unroll
        for (int nf = 0; nf < 2; ++nf) { b1[nf][0] = LDB(cb, 1, nf, 0); b1[nf][1] = LDB(cb, 1, nf, 1); }
        __builtin_amdgcn_s_barrier();
        __builtin_amdgcn_s_setprio(1);
#pragma unroll
        for (int mf = 0; mf < 4; ++mf)
#pragma unroll
            for (int nf = 0; nf < 2; ++nf)
#pragma unroll
                for (int ks = 0; ks < 2; ++ks)
                    acc[mf][2 + nf] = mfma16(a[mf][ks], b1[nf][ks], acc[mf][2 + nf]);
        __builtin_amdgcn_s_setprio(0);
        asm volatile("s_waitcnt lgkmcnt(0)" ::: "memory");
        __builtin_amdgcn_s_barrier();

        // ===== ph3: (mh1, nh1); stage B(t+2) =====
#pragma unroll
        for (int mf = 0; mf < 4; ++mf) { a[mf][0] = LDA(cb, 1, mf, 0); a[mf][1] = LDA(cb, 1, mf, 1); }
        if (more) STAGE_MAT(Bg, 65536, t + 2, cb);
        __builtin_amdgcn_s_barrier();
        __builtin_amdgcn_s_setprio(1);
#pragma unroll
        for (int mf = 0; mf < 4; ++mf)
#pragma unroll
            for (int nf = 0; nf < 2; ++nf)
#pragma unroll
                for (int ks = 0; ks < 2; ++ks)
                    acc[4 + mf][2 + nf] = mfma16(a[mf][ks], b1[nf][ks], acc[4 + mf][2 + nf]);
        __builtin_amdgcn_s_setprio(0);
        asm volatile("s_waitcnt lgkmcnt(0)" ::: "memory");
        __builtin_amdgcn_s_barrier();

        // ===== ph4: (mh1, nh0); stage A(t+2) =====
        if (more) STAGE_MAT(Ag, 0, t + 2, cb);
        __builtin_amdgcn_s_barrier();
        __builtin_amdgcn_s_setprio(1);
#pragma unroll
        for (int mf = 0; mf < 4; ++mf)
#pragma unroll
            for (int nf = 0; nf < 2; ++nf)
#pragma unroll
                for (int ks = 0; ks < 2; ++ks)
                    acc[4 + mf][nf] = mfma16(a[mf][ks], b0[nf][ks], acc[4 + mf][nf]);
        __builtin_amdgcn_s_setprio(0);
        if (t < nt - 1) {
            if (t == nt - 2) asm volatile("s_waitcnt vmcnt(0) lgkmcnt(0)" ::: "memory");
            else             asm volatile("s_waitcnt vmcnt(8) lgkmcnt(0)" ::: "memory");
            __builtin_amdgcn_s_barrier();
        }
    }
#undef STAGE_MAT
#undef LDA
#undef LDB

#pragma unroll
    for (int mf = 0; mf < 8; ++mf)
#pragma unroll
        for (int nf = 0; nf < 4; ++nf)
#pragma unroll
            for (int r = 0; r < 4; ++r) {
                int row = brow + wrow * 128 + mf * 16 + lg * 4 + r;
                int col = bcol + wcol * 64 + nf * 16 + lq;
                store_out(&C[(size_t)row * N + col], acc[mf][nf][r]);
            }
}

// ---------------- RoPE for q or k (optional pre-scale folded in) ----------------
__global__ __launch_bounds__(256) void rope_qk(const bf16* __restrict__ qkv,
                                               bf16* __restrict__ outp,
                                               int nheads, int col_off, float qscale) {
    size_t idx = (size_t)blockIdx.x * 256 + threadIdx.x;  // (b,h,t,i) i<64
    int i = (int)(idx & 63);
    size_t rest = idx >> 6;
    int t = (int)(rest % T_);
    rest /= T_;
    int hh = (int)(rest % nheads);
    int b = (int)(rest / nheads);

    const bf16* src = qkv + (size_t)(b * T_ + t) * QKVN_ + col_off + hh * HD_;
    float x0 = __bfloat162float(src[i]);
    float x1 = __bfloat162float(src[i + 64]);
    float inv = exp2f((float)i * -0.20762050593045952f);
    float th = (float)t * inv;
    float s = sinf(th), c = cosf(th);
    bf16* dst = outp + ((size_t)(b * nheads + hh) * T_ + t) * HD_;
    dst[i]      = __float2bfloat16((x0 * c - x1 * s) * qscale);
    dst[i + 64] = __float2bfloat16((x1 * c + x0 * s) * qscale);
}

// ---------------- V transpose: qkv v-slice [B,T,NKV,HD] -> vt [B,NKV,HD,T] ----------------
__global__ __launch_bounds__(256) void vtrans(const bf16* __restrict__ qkv,
                                              bf16* __restrict__ vt) {
    __shared__ bf16 tile[32][33];
    int gx = blockIdx.x;               // [b(1)|kv(3)|tt(6)|dt(2)]
    int dt = gx & 3;
    int tt = (gx >> 2) & 63;
    int kv = (gx >> 8) & 7;
    int b  = gx >> 11;
    int d0 = dt * 32, t0 = tt * 32;
    int tx = threadIdx.x & 31, ty = threadIdx.x >> 5;

    const bf16* src = qkv + (size_t)(b * T_ + t0) * QKVN_ + (NH_*HD_ + NKV_*HD_) + kv * HD_ + d0;
#pragma unroll
    for (int p = 0; p < 4; ++p)
        tile[p*8 + ty][tx] = src[(size_t)(p*8 + ty) * QKVN_ + tx];
    __syncthreads();
    bf16* dst = vt + ((size_t)((b * NKV_ + kv) * HD_ + d0)) * T_ + t0;
#pragma unroll
    for (int p = 0; p < 4; ++p)
        dst[(size_t)(p*8 + ty) * T_ + tx] = tile[tx][p*8 + ty];
}

// ---------------- Flash attention (causal, GQA), load-balanced ----------------
// Q [B,NH,T,HD] (pre-scaled by HD^-0.5), K [B,NKV,T,HD], VT [B,NKV,HD,T] -> O [B,T,NH,HD]
// 512 blocks, flash-2 causal pairing (qb = jp then 15-jp) -> ~equal work/block.
// kv = lin&7 keeps each kv-head's K/V on one XCD's L2.
// Per wave: 32 q rows, KV tile = 64 keys.
// VMEM ISSUE ORDER MATTERS (vmcnt is in-order): all 16 K loads FIRST, then V
// (QK's kf waits then never force V completion; V lands under softmax).
__global__ __launch_bounds__(256) void fattn(const bf16* __restrict__ Q,
                                             const bf16* __restrict__ Kt,
                                             const bf16* __restrict__ VT,
                                             bf16* __restrict__ O) {
    const int lin = blockIdx.x;          // 512 blocks
    const int kv = lin & 7;
    const int b  = (lin >> 3) & 1;
    const int idx = lin >> 4;            // 0..31
    const int h  = kv * 4 + (idx & 3);   // GROUPS=4
    const int jp = idx >> 2;             // 0..7 pair index

    const int tid = threadIdx.x, wid = tid >> 6, lane = tid & 63;
    const int lq = lane & 15, lg = lane >> 4;

    const bf16* Kp = Kt + (size_t)(b * NKV_ + kv) * T_ * HD_;
    const bf16* Vp = VT + (size_t)(b * NKV_ + kv) * HD_ * T_;

    __shared__ __align__(16) bf16 p_lds[4][32][72];

    for (int half = 0; half < 2; ++half) {
        const int qb = half ? (15 - jp) : jp;
        const int q0 = qb * 128 + wid * 32;   // this wave's 32 q rows

        const bf16* Qp = Q + ((size_t)(b * NH_ + h) * T_ + q0) * HD_;
        bf16x8 qf[2][4];
#pragma unroll
        for (int m = 0; m < 2; ++m)
#pragma unroll
            for (int c = 0; c < 4; ++c)
                qf[m][c] = *(const bf16x8*)&Qp[(size_t)(m*16 + lq) * HD_ + c * 32 + lg * 8];

        f32x4 oacc[2][8] = {};
        float m_r[2][4], l_r[2][4];
#pragma unroll
        for (int m = 0; m < 2; ++m)
#pragma unroll
            for (int r = 0; r < 4; ++r) { m_r[m][r] = -INFINITY; l_r[m][r] = 0.f; }

        const int kv_end = q0 + 32;   // per-wave causal bound

        for (int t0 = 0; t0 < kv_end; t0 += 64) {
            // ---- K: ALL 16 fragments issued first ----
            bf16x8 kf[4][4];
#pragma unroll
            for (int n = 0; n < 4; ++n)
#pragma unroll
                for (int c = 0; c < 4; ++c)
                    kf[n][c] = *(const bf16x8*)&Kp[(size_t)(t0 + n*16 + lq) * HD_ + c * 32 + lg * 8];

            // ---- V ks=0: issued AFTER K -> in flight during QK + softmax ----
            bf16x8 vf0[8];
#pragma unroll
            for (int f = 0; f < 8; ++f)
                vf0[f] = *(const bf16x8*)&Vp[(size_t)(f*16 + lq) * T_ + t0 + lg * 8];

            // ---- S = Q @ K^T : 32 x 64 ----
            f32x4 s[2][4] = {};
            __builtin_amdgcn_s_setprio(1);
#pragma unroll
            for (int n = 0; n < 4; ++n)
#pragma unroll
                for (int c = 0; c < 4; ++c) {
                    s[0][n] = mfma16(qf[0][c], kf[n][c], s[0][n]);
                    s[1][n] = mfma16(qf[1][c], kf[n][c], s[1][n]);
                }
            __builtin_amdgcn_s_setprio(0);

            // ---- causal mask (Q pre-scaled) ----
#pragma unroll
            for (int m = 0; m < 2; ++m)
#pragma unroll
                for (int n = 0; n < 4; ++n)
#pragma unroll
                    for (int r = 0; r < 4; ++r) {
                        int kk = t0 + n*16 + lq;
                        int qq = q0 + m*16 + lg*4 + r;
                        if (kk > qq) s[m][n][r] = -INFINITY;
                    }

            // ---- row max + defer-max (THR=8) ----
            float rmax[2][4];
#pragma unroll
            for (int m = 0; m < 2; ++m)
#pragma unroll
                for (int r = 0; r < 4; ++r) {
                    float v = fmaxf(fmaxf(s[m][0][r], s[m][1][r]),
                                    fmaxf(s[m][2][r], s[m][3][r]));
#pragma unroll
                    for (int off = 8; off >= 1; off >>= 1)
                        v = fmaxf(v, __shfl_xor(v, off));
                    rmax[m][r] = v;
                }
            float dmax = -INFINITY;
#pragma unroll
            for (int m = 0; m < 2; ++m)
#pragma unroll
                for (int r = 0; r < 4; ++r)
                    dmax = fmaxf(dmax, rmax[m][r] - m_r[m][r]);
            if (__any(dmax > 8.0f)) {
#pragma unroll
                for (int m = 0; m < 2; ++m)
#pragma unroll
                    for (int r = 0; r < 4; ++r) {
                        float mnew = fmaxf(m_r[m][r], rmax[m][r]);
                        float alpha = __expf(m_r[m][r] - mnew);   // first tile: exp(-inf)=0
                        m_r[m][r] = mnew;
                        l_r[m][r] *= alpha;
#pragma unroll
                        for (int f = 0; f < 8; ++f) oacc[m][f][r] *= alpha;
                    }
            }

            // ---- exp + row sum ----
#pragma unroll
            for (int m = 0; m < 2; ++m)
#pragma unroll
                for (int r = 0; r < 4; ++r) {
                    float rsum = 0.f;
#pragma unroll
                    for (int n = 0; n < 4; ++n) {
                        float p = __expf(s[m][n][r] - m_r[m][r]);   // bounded by e^8
                        s[m][n][r] = p;
                        rsum += p;
                    }
#pragma unroll
                    for (int off = 8; off >= 1; off >>= 1)
                        rsum += __shfl_xor(rsum, off);
                    l_r[m][r] += rsum;
                }

            // ---- P -> LDS -> A-fragments ----
#pragma unroll
            for (int m = 0; m < 2; ++m)
#pragma unroll
                for (int n = 0; n < 4; ++n)
#pragma unroll
                    for (int r = 0; r < 4; ++r)
                        p_lds[wid][m*16 + lg*4 + r][n*16 + lq] = __float2bfloat16(s[m][n][r]);
            bf16x8 pa00 = *(const bf16x8*)&p_lds[wid][lq]     [lg * 8];
            bf16x8 pa10 = *(const bf16x8*)&p_lds[wid][16 + lq][lg * 8];

            // ---- O += P @ V (ks=0) ----
            __builtin_amdgcn_s_setprio(1);
#pragma unroll
            for (int f = 0; f < 8; ++f) {
                oacc[0][f] = mfma16(pa00, vf0[f], oacc[0][f]);
                oacc[1][f] = mfma16(pa10, vf0[f], oacc[1][f]);
            }
            __builtin_amdgcn_s_setprio(0);

            // ---- V ks=1 (vf0 regs dying; loads overlap PV0 issue) ----
            bf16x8 vf1[8];
#pragma unroll
            for (int f = 0; f < 8; ++f)
                vf1[f] = *(const bf16x8*)&Vp[(size_t)(f*16 + lq) * T_ + t0 + 32 + lg * 8];
            bf16x8 pa01 = *(const bf16x8*)&p_lds[wid][lq]     [32 + lg * 8];
            bf16x8 pa11 = *(const bf16x8*)&p_lds[wid][16 + lq][32 + lg * 8];

            // ---- O += P @ V (ks=1) ----
            __builtin_amdgcn_s_setprio(1);
#pragma unroll
            for (int f = 0; f < 8; ++f) {
                oacc[0][f] = mfma16(pa01, vf1[f], oacc[0][f]);
                oacc[1][f] = mfma16(pa11, vf1[f], oacc[1][f]);
            }
            __builtin_amdgcn_s_setprio(0);
        }

        // ---- epilogue: multiply by 1/l (v_rcp), store [B,T,NH,HD] ----
#pragma unroll
        for (int m = 0; m < 2; ++m) {
            float rl[4];
#pragma unroll
            for (int r = 0; r < 4; ++r) rl[r] = __builtin_amdgcn_rcpf(l_r[m][r]);
#pragma unroll
            for (int f = 0; f < 8; ++f)
#pragma unroll
                for (int r = 0; r < 4; ++r) {
                    int row = q0 + m*16 + lg*4 + r;
                    int d = f*16 + lq;
                    float v = oacc[m][f][r] * rl[r];
                    O[((size_t)(b * T_ + row) * NH_ + h) * HD_ + d] = __float2bfloat16(v);
                }
        }
    }
}

// ---------------- launch ----------------
extern "C" void kernel_launch(void* const* d_in, const int* in_sizes, int n_in,
                              void* d_out, int out_size, void* d_ws, size_t ws_size,
                              hipStream_t stream) {
    const float* x  = (const float*)d_in[0];
    const float* wq = (const float*)d_in[1];
    const float* wk = (const float*)d_in[2];
    const float* wv = (const float*)d_in[3];
    const float* wo = (const float*)d_in[4];
    float* out = (float*)d_out;

    bf16* ws    = (bf16*)d_ws;
    bf16* xb    = ws;
    bf16* wqkvT = xb + (size_t)M_ * C_;
    bf16* woT   = wqkvT + (size_t)QKVN_ * C_;
    bf16* qkv   = woT + (size_t)C_ * C_;

    bf16* attn = xb;                                  // reuse after QKV GEMM
    bf16* q_r  = wqkvT;                               // reuse after QKV GEMM
    bf16* k_r  = q_r + (size_t)B_ * NH_ * T_ * HD_;
    bf16* vt   = k_r + (size_t)B_ * NKV_ * T_ * HD_;

    // 1) casts / transposes
    cast_f32_bf16<<<(M_ * C_ / 4 + 255) / 256, 256, 0, stream>>>(x, xb, M_ * C_ / 4);
    transpose_cast<<<dim3(128, 128), 256, 0, stream>>>(wq, wqkvT, C_, NH_ * HD_);
    transpose_cast<<<dim3(32, 128), 256, 0, stream>>>(wk, wqkvT + (size_t)(NH_ * HD_) * C_, C_, NKV_ * HD_);
    transpose_cast<<<dim3(32, 128), 256, 0, stream>>>(wv, wqkvT + (size_t)(NH_ * HD_ + NKV_ * HD_) * C_, C_, NKV_ * HD_);
    transpose_cast<<<dim3(128, 128), 256, 0, stream>>>(wo, woT, NH_ * HD_, C_);

    // 2) fused QKV GEMM
    gemm256<bf16><<<dim3((QKVN_ / 256) * (M_ / 256)), 512, 0, stream>>>(xb, wqkvT, qkv, M_, QKVN_, C_);

    // 3) RoPE (Q pre-scaled by 1/sqrt(HD)) + layout transforms
    rope_qk<<<(B_ * NH_ * T_ * 64) / 256, 256, 0, stream>>>(qkv, q_r, NH_, 0, 0.08838834764831843f);
    rope_qk<<<(B_ * NKV_ * T_ * 64) / 256, 256, 0, stream>>>(qkv, k_r, NKV_, NH_ * HD_, 1.0f);
    vtrans<<<B_ * NKV_ * (T_ / 32) * (HD_ / 32), 256, 0, stream>>>(qkv, vt);

    // 4) attention (512 balanced blocks)
    fattn<<<dim3(512), 256, 0, stream>>>(q_r, k_r, vt, attn);

    // 5) output projection
    gemm256<float><<<dim3((C_ / 256) * (M_ / 256)), 512, 0, stream>>>(attn, woT, out, M_, C_, C_);
}